// Round 1
// baseline (59.981 us; speedup 1.0000x reference)
//
#include <hip/hip_runtime.h>

// HiPoNet collapse: P = 0.5*colnorm(Wm) + 0.5*I is column-stochastic
// (1^T P = 1^T), so mean-pool(P^t X) == mean-pool(X) for every t.
// Output[b, w, k*32+j] = mean_n(pc[b,n,j]) * alphas[w,j] for k=0..4.
//
// Single fused kernel: one block per batch element. Each block reads its
// full 256 KB slice (1024 threads x 16 float4, coalesced, 16 waves hide
// latency), reduces 32 column sums via in-wave __shfl_xor (lanes sharing
// lane&7 hold the same 4-column group), and writes its 640 outputs
// directly. No workspace, no second dispatch, no serial 1-block combine.
// The harness's 256 MB ws poison fill (~40 us) runs regardless of ws use.

#define NPTS   2048
#define DIM    32
#define BATCH  4
#define NW     4
#define NFEAT  5
#define OUT_PER_B (NW * NFEAT * DIM)     // 640
#define THREADS   1024
#define F4_PER_B  (NPTS * DIM / 4)       // 16384 float4 per batch slice
#define LOADS     (F4_PER_B / THREADS)   // 16 per thread

__global__ __launch_bounds__(THREADS) void fused_mean_outer(
        const float* __restrict__ pc,
        const float* __restrict__ alphas,
        float* __restrict__ out) {
    const int b = blockIdx.x;
    const int t = threadIdx.x;

    // Coalesced read of this batch's [2048 x 32] slice. Stride 1024 float4:
    // (t + i*1024) & 7 == t & 7, so each thread stays in one 4-column group.
    const float4* base = (const float4*)(pc + (size_t)b * NPTS * DIM);
    float4 s = make_float4(0.f, 0.f, 0.f, 0.f);
#pragma unroll
    for (int i = 0; i < LOADS; ++i) {
        float4 v = base[t + i * THREADS];
        s.x += v.x; s.y += v.y; s.z += v.z; s.w += v.w;
    }

    // In-wave reduce: xor offsets 8/16/32 sum all lanes with equal (lane&7).
#pragma unroll
    for (int off = 8; off < 64; off <<= 1) {
        s.x += __shfl_xor(s.x, off, 64);
        s.y += __shfl_xor(s.y, off, 64);
        s.z += __shfl_xor(s.z, off, 64);
        s.w += __shfl_xor(s.w, off, 64);
    }

    __shared__ float4 sm[(THREADS / 64) * 8];   // 16 waves x 8 groups = 128
    __shared__ float  colmean[DIM];
    const int wave = t >> 6, lane = t & 63;
    if (lane < 8) sm[wave * 8 + lane] = s;
    __syncthreads();

    if (t < 64) {
        float4 a = sm[t];
        float4 c = sm[t + 64];
        a.x += c.x; a.y += c.y; a.z += c.z; a.w += c.w;
#pragma unroll
        for (int off = 8; off < 64; off <<= 1) {
            a.x += __shfl_xor(a.x, off, 64);
            a.y += __shfl_xor(a.y, off, 64);
            a.z += __shfl_xor(a.z, off, 64);
            a.w += __shfl_xor(a.w, off, 64);
        }
        if (t < 8) {
            colmean[t * 4 + 0] = a.x * (1.0f / NPTS);
            colmean[t * 4 + 1] = a.y * (1.0f / NPTS);
            colmean[t * 4 + 2] = a.z * (1.0f / NPTS);
            colmean[t * 4 + 3] = a.w * (1.0f / NPTS);
        }
    }
    __syncthreads();

    // 640 outputs for this b: out[b, w, k*32+j] = colmean[j] * alphas[w,j].
    if (t < OUT_PER_B) {
        const int j = t & 31;
        const int w = t / (NFEAT * DIM);
        out[b * OUT_PER_B + t] = colmean[j] * alphas[w * DIM + j];
    }
}

extern "C" void kernel_launch(void* const* d_in, const int* in_sizes, int n_in,
                              void* d_out, int out_size, void* d_ws, size_t ws_size,
                              hipStream_t stream) {
    const float* pc     = (const float*)d_in[0];   // [4, 2048, 32] fp32
    // d_in[1] = sigma — unused: pooled output is sigma/threshold-invariant
    const float* alphas = (const float*)d_in[2];   // [4, 32] fp32
    float*       out    = (float*)d_out;           // [4, 640] fp32
    (void)d_ws; (void)ws_size;

    fused_mean_outer<<<BATCH, THREADS, 0, stream>>>(pc, alphas, out);
}

// Round 2
// 57.956 us; speedup vs baseline: 1.0349x; 1.0349x over previous
//
#include <hip/hip_runtime.h>

// HiPoNet collapse: P = 0.5*colnorm(Wm) + 0.5*I is column-stochastic
// (1^T P = 1^T), so mean-pool(P^t X) == mean-pool(X) for every t.
// Output[b, w, k*32+j] = mean_n(pc[b,n,j]) * alphas[w,j] for k=0..4.
//
// Two tiny kernels: 64-block parallel partial-sum (reads 1 MB spread
// across 64 CUs instead of 4), then a one-block combine+outer-product.
// d_ws holds plain-store partials (no init needed, no atomics); the
// harness's 256 MB ws poison fill (~40 us @ 84% HBM peak) plus its
// restore dispatches (~14 us) dominate dur_us and are fixed overhead.
// Round-1 experiment: fully-fused 4-block single dispatch measured
// 60.0 us vs this structure's 57.8 us — the saved dispatch was repaid
// by serializing all reads onto 4 CUs. Keeping the measured-best form.

#define NPTS   2048
#define DIM    32
#define BATCH  4
#define NW     4
#define NFEAT  5
#define BLK_PER_B 16
#define NBLK   (BATCH * BLK_PER_B)       // 64
#define ROWS   (NPTS / BLK_PER_B)        // 128 rows per block
#define OUT_PER_B (NW * NFEAT * DIM)     // 640
#define OUT_TOTAL (BATCH * OUT_PER_B)    // 2560

__global__ __launch_bounds__(256) void partial_sums(const float* __restrict__ pc,
                                                    float* __restrict__ ws) {
    const int b   = blockIdx.x / BLK_PER_B;
    const int blk = blockIdx.x % BLK_PER_B;
    const int t   = threadIdx.x;

    // This block's slice: 128 rows x 32 cols = 1024 float4, coalesced.
    const float4* base = (const float4*)(pc + (size_t)b * NPTS * DIM
                                            + (size_t)blk * ROWS * DIM);
    float4 s = make_float4(0.f, 0.f, 0.f, 0.f);
#pragma unroll
    for (int i = 0; i < 4; ++i) {
        float4 v = base[t + i * 256];   // (t+256i)&7 == t&7: fixed column group
        s.x += v.x; s.y += v.y; s.z += v.z; s.w += v.w;
    }

    __shared__ float4 sm[256];
    sm[t] = s;
    __syncthreads();
#pragma unroll
    for (int str = 128; str >= 8; str >>= 1) {   // strides stay multiples of 8
        if (t < str) {
            float4 a = sm[t], c = sm[t + str];
            a.x += c.x; a.y += c.y; a.z += c.z; a.w += c.w;
            sm[t] = a;
        }
        __syncthreads();
    }
    // sm[0..7] flat = 32 column sums for this block's 128 rows.
    if (t < DIM)
        ws[blockIdx.x * DIM + t] = ((const float*)sm)[t];
}

__global__ __launch_bounds__(256) void combine(const float* __restrict__ ws,
                                               const float* __restrict__ alphas,
                                               float* __restrict__ out) {
    const int t = threadIdx.x;
    __shared__ float mean[BATCH * DIM];   // 128

    if (t < BATCH * DIM) {
        const int b = t >> 5, j = t & 31;
        float s = 0.f;
#pragma unroll
        for (int k = 0; k < BLK_PER_B; ++k)
            s += ws[(b * BLK_PER_B + k) * DIM + j];
        mean[t] = s * (1.0f / NPTS);
    }
    __syncthreads();

#pragma unroll
    for (int i = 0; i < OUT_TOTAL / 256; ++i) {   // 10 outputs per thread
        const int idx = t + i * 256;
        const int b = idx / OUT_PER_B;
        const int r = idx % OUT_PER_B;
        const int j = r & 31;
        const int w = r / (NFEAT * DIM);
        out[idx] = mean[b * DIM + j] * alphas[w * DIM + j];
    }
}

extern "C" void kernel_launch(void* const* d_in, const int* in_sizes, int n_in,
                              void* d_out, int out_size, void* d_ws, size_t ws_size,
                              hipStream_t stream) {
    const float* pc     = (const float*)d_in[0];   // [4, 2048, 32] fp32
    // d_in[1] = sigma — unused: pooled output is sigma/threshold-invariant
    const float* alphas = (const float*)d_in[2];   // [4, 32] fp32
    float*       out    = (float*)d_out;           // [4, 640] fp32
    float*       ws     = (float*)d_ws;            // 64*32 partial sums

    partial_sums<<<NBLK, 256, 0, stream>>>(pc, ws);
    combine<<<1, 256, 0, stream>>>(ws, alphas, out);
}